// Round 5
// baseline (266.907 us; speedup 1.0000x reference)
//
#include <hip/hip_runtime.h>
#include <float.h>
#include <math.h>

#define BATCH 8
#define NPTS 4096
#define KNN 10
#define BN (BATCH * NPTS)          // 32768 points per cloud
#define NCLOUD (2 * BATCH)         // 16 clouds (pred+gt) x batch
#define CHUNK 64                   // candidates per staged step
#define QPB 64                     // queries per block (1 per lane)

__device__ float4 g_spts[NCLOUD * NPTS];  // x-sorted (x, y, z, |p|^2)
__device__ int    g_perm[NCLOUD * NPTS];  // sorted pos -> original idx
__device__ float4 g_nrm[2 * BN];          // normals in original order

__device__ inline float med3f(float x, float a, float b) {
    return __builtin_amdgcn_fmed3f(x, a, b);
}

// branchless sorted insert of key into ascending k[0..9] (drop largest);
// all 9 med3 read pre-insert values -> mutually independent
#define INSERT(karr, key)                                              \
    do {                                                               \
        _Pragma("unroll")                                              \
        for (int _j = KNN - 1; _j >= 1; --_j)                          \
            karr[_j] = med3f((key), karr[_j - 1], karr[_j]);           \
        karr[0] = fminf((key), karr[0]);                               \
    } while (0)

// distance + pack(sorted idx, 12 bits) + insert; d bit-identical to the
// brute-force kernel (coords are exact copies, same fma chain)
#define PROC1(_p, _gi)                                                 \
    do {                                                               \
        float _d = fmaf((_p).z, a0z, fmaf((_p).y, a0y, fmaf((_p).x, a0x, (_p).w))); \
        float _k = __uint_as_float((__float_as_uint(_d) & 0xFFFFF000u) | (unsigned)(_gi)); \
        INSERT(kq, _k);                                                \
    } while (0)

// conservative prune threshold ~ d10^2: kq[9]+qw reconstructs d10^2 up to
// the 12-bit key truncation (<= ~1e-3 relative) -> margin keeps decisions
// a superset of the brute-force kernel's inserts (exactness preserved)
#define RETHR() (kq[KNN - 1] + qw + fmaf(fabsf(kq[KNN - 1]), 2e-3f, 1e-4f))

// stage 64 candidates (global->LDS via reg, wave-private buffer, no barrier:
// same-wave ds_write -> ds_read ordered by lgkmcnt) then 8x8 insert sweep
#define DOCHUNK(_lo)                                                   \
    do {                                                               \
        wbuf[w][lane] = g_spts[cb + (_lo) + lane];                     \
        _Pragma("unroll")                                              \
        for (int _cc = 0; _cc < CHUNK; _cc += 8) {                     \
            float4 C0 = wbuf[w][_cc + 0], C1 = wbuf[w][_cc + 1];       \
            float4 C2 = wbuf[w][_cc + 2], C3 = wbuf[w][_cc + 3];       \
            float4 C4 = wbuf[w][_cc + 4], C5 = wbuf[w][_cc + 5];       \
            float4 C6 = wbuf[w][_cc + 6], C7 = wbuf[w][_cc + 7];       \
            PROC1(C0, (_lo) + _cc + 0);                                \
            PROC1(C1, (_lo) + _cc + 1);                                \
            PROC1(C2, (_lo) + _cc + 2);                                \
            PROC1(C3, (_lo) + _cc + 3);                                \
            PROC1(C4, (_lo) + _cc + 4);                                \
            PROC1(C5, (_lo) + _cc + 5);                                \
            PROC1(C6, (_lo) + _cc + 6);                                \
            PROC1(C7, (_lo) + _cc + 7);                                \
        }                                                              \
    } while (0)

// Eigenvector of smallest eigenvalue of symmetric 3x3
__device__ inline void smallest_eigvec(float a00, float a01, float a02,
                                       float a11, float a12, float a22,
                                       float& vx, float& vy, float& vz) {
    float p1 = a01 * a01 + a02 * a02 + a12 * a12;
    float q = (a00 + a11 + a22) * (1.0f / 3.0f);
    float b00 = a00 - q, b11 = a11 - q, b22 = a22 - q;
    float p2 = b00 * b00 + b11 * b11 + b22 * b22 + 2.0f * p1;
    float p = sqrtf(p2 * (1.0f / 6.0f));
    if (p < 1e-20f) { vx = 1.0f; vy = 0.0f; vz = 0.0f; return; }
    float ip = 1.0f / p;
    float c00 = b00 * ip, c01 = a01 * ip, c02 = a02 * ip;
    float c11 = b11 * ip, c12 = a12 * ip, c22 = b22 * ip;
    float detB = c00 * (c11 * c22 - c12 * c12)
               - c01 * (c01 * c22 - c12 * c02)
               + c02 * (c01 * c12 - c11 * c02);
    float r = 0.5f * detB;
    r = fminf(1.0f, fmaxf(-1.0f, r));
    float phi = acosf(r) * (1.0f / 3.0f);
    float lmin = q + 2.0f * p * cosf(phi + 2.0943951023931953f);

    float m00 = a00 - lmin, m11 = a11 - lmin, m22 = a22 - lmin;
    float r0x = m00, r0y = a01, r0z = a02;
    float r1x = a01, r1y = m11, r1z = a12;
    float r2x = a02, r2y = a12, r2z = m22;
    float c0x = r0y * r1z - r0z * r1y, c0y = r0z * r1x - r0x * r1z, c0z = r0x * r1y - r0y * r1x;
    float c1x = r0y * r2z - r0z * r2y, c1y = r0z * r2x - r0x * r2z, c1z = r0x * r2y - r0y * r2x;
    float c2x = r1y * r2z - r1z * r2y, c2y = r1z * r2x - r1x * r2z, c2z = r1x * r2y - r1y * r2x;
    float n0 = c0x * c0x + c0y * c0y + c0z * c0z;
    float n1 = c1x * c1x + c1y * c1y + c1z * c1z;
    float n2 = c2x * c2x + c2y * c2y + c2z * c2z;
    float bx = c0x, by = c0y, bz = c0z, bnm = n0;
    if (n1 > bnm) { bx = c1x; by = c1y; bz = c1z; bnm = n1; }
    if (n2 > bnm) { bx = c2x; by = c2y; bz = c2z; bnm = n2; }
    if (bnm < 1e-30f) { vx = 1.0f; vy = 0.0f; vz = 0.0f; return; }
    float inv = rsqrtf(bnm);
    vx = bx * inv; vy = by * inv; vz = bz * inv;
}

__global__ void zero_out_kernel(float* __restrict__ out) {
    if (threadIdx.x == 0) out[0] = 0.0f;
}

// one block per cloud: in-LDS bitonic sort of 4096 (x, idx) pairs, then
// emit sorted float4 (x,y,z,|p|^2) + permutation
__global__ __launch_bounds__(1024) void sort_clouds(
    const float* __restrict__ pred, const float* __restrict__ gt) {
    __shared__ float skey[NPTS];
    __shared__ int   sidx[NPTS];
    const int c = blockIdx.x;
    const float* __restrict__ base =
        (c >= BATCH) ? (gt + (c - BATCH) * 3 * NPTS) : (pred + c * 3 * NPTS);
    const int tid = threadIdx.x;

    for (int i = tid; i < NPTS; i += 1024) { skey[i] = base[i]; sidx[i] = i; }

    for (int k = 2; k <= NPTS; k <<= 1) {
        for (int j = k >> 1; j > 0; j >>= 1) {
            __syncthreads();
            for (int t = tid; t < NPTS / 2; t += 1024) {
                int i = ((t / j) * 2 * j) + (t % j);
                int p = i + j;
                bool up = ((i & k) == 0);
                float a = skey[i], bb = skey[p];
                bool sw = up ? (a > bb) : (a < bb);
                if (sw) {
                    skey[i] = bb; skey[p] = a;
                    int ia = sidx[i]; sidx[i] = sidx[p]; sidx[p] = ia;
                }
            }
        }
    }
    __syncthreads();

    const int cb = c * NPTS;
    for (int i = tid; i < NPTS; i += 1024) {
        int idx = sidx[i];
        float x = skey[i];
        float y = base[NPTS + idx];
        float z = base[2 * NPTS + idx];
        g_spts[cb + i] = make_float4(x, y, z, fmaf(x, x, fmaf(y, y, z * z)));
        g_perm[cb + i] = idx;
    }
}

// One block = 64 consecutive x-sorted queries of one cloud, 2 waves:
// wave 0 expands LEFT, wave 1 expands RIGHT; both seed on the query chunk.
// Per-direction termination: all unseen candidates have |dx| >= edge |dx|,
// so stop when edge dx^2 >= thr for every lane (exact prune).
// Grid (cloud, group): consecutive dispatch ids vary cloud first, so each
// CU receives a spread of window sizes (center + edge) -> load balance.
__global__ __launch_bounds__(128) void knn_window() {
    __shared__ float4 wbuf[2][CHUNK];     // per-wave staging (wave-private)
    __shared__ float  keybuf[QPB][KNN];   // wave-0 results for the merge

    const int c  = blockIdx.x;            // cloud 0..15
    const int bx = blockIdx.y;            // query group 0..63
    const int cb = c * NPTS;
    const int tid  = threadIdx.x;
    const int lane = tid & 63;
    const int w    = tid >> 6;            // 0 = left, 1 = right
    const int s0 = bx * QPB;
    const int s  = s0 + lane;             // my sorted query position

    const float4 qp = g_spts[cb + s];
    const float qx = qp.x, qw = qp.w;
    const float a0x = -2.0f * qp.x, a0y = -2.0f * qp.y, a0z = -2.0f * qp.z;

    float kq[KNN];
#pragma unroll
    for (int j = 0; j < KNN; ++j) kq[j] = FLT_MAX;

    // seed: the 64 candidates at the query positions (fills all 10 slots)
    DOCHUNK(s0);
    float thr = RETHR();

    if (w == 0) {
        int lo = s0;
        while (lo > 0) {
            float xe = wbuf[0][0].x;              // leftmost processed x
            float dx = qx - xe;                   // >= 0 (sorted)
            if (__all(dx * dx >= thr)) break;
            lo -= CHUNK;
            DOCHUNK(lo);
            thr = RETHR();
        }
    } else {
        int hi = s0;
        while (hi + CHUNK < NPTS) {
            float xe = wbuf[1][CHUNK - 1].x;      // rightmost processed x
            float dx = xe - qx;                   // >= 0 (sorted)
            if (__all(dx * dx >= thr)) break;
            hi += CHUNK;
            DOCHUNK(hi);
            thr = RETHR();
        }
    }

    // merge: wave 0 publishes, wave 1 folds in + finishes the query
    if (w == 0) {
#pragma unroll
        for (int j = 0; j < KNN; ++j) keybuf[lane][j] = kq[j];
    }
    __syncthreads();
    if (w == 1) {
#pragma unroll
        for (int j = 0; j < KNN; ++j) { float v = keybuf[lane][j]; INSERT(kq, v); }

        float sx = 0.f, sy = 0.f, sz = 0.f;
        float sxx = 0.f, sxy = 0.f, sxz = 0.f;
        float syy = 0.f, syz = 0.f, szz = 0.f;
#pragma unroll
        for (int j = 0; j < KNN; ++j) {
            int sidx = (int)(__float_as_uint(kq[j]) & 0xFFFu);
            float4 nb = g_spts[cb + sidx];        // L2-hot gather
            sx += nb.x; sy += nb.y; sz += nb.z;
            sxx = fmaf(nb.x, nb.x, sxx); sxy = fmaf(nb.x, nb.y, sxy); sxz = fmaf(nb.x, nb.z, sxz);
            syy = fmaf(nb.y, nb.y, syy); syz = fmaf(nb.y, nb.z, syz); szz = fmaf(nb.z, nb.z, szz);
        }
        const float iK = 1.0f / KNN;
        float mx = sx * iK, my = sy * iK, mz = sz * iK;
        float vx, vy, vz;
        smallest_eigvec(sxx * iK - mx * mx, sxy * iK - mx * my,
                        sxz * iK - mx * mz, syy * iK - my * my,
                        syz * iK - my * mz, szz * iK - mz * mz,
                        vx, vy, vz);
        const int cs = c >> 3, b = c & 7;
        const int oq = g_perm[cb + s];            // scatter to original order
        g_nrm[cs * BN + b * NPTS + oq] = make_float4(vx, vy, vz, 0.f);
    }
}

// loss over 32768 point pairs; one wave-sum atomic per 64 lanes
__global__ __launch_bounds__(256) void cos_loss_kernel(float* __restrict__ out) {
    const int i = blockIdx.x * 256 + threadIdx.x;     // grid sized exactly BN
    float4 p = g_nrm[i];
    float4 g = g_nrm[BN + i];
    float dot = p.x * g.x + p.y * g.y + p.z * g.z;
    float npn = sqrtf(p.x * p.x + p.y * p.y + p.z * p.z);
    float ngn = sqrtf(g.x * g.x + g.y * g.y + g.z * g.z);
    float acc = 1.0f - fabsf(dot / fmaxf(npn * ngn, 1e-8f));
    for (int off = 32; off > 0; off >>= 1) acc += __shfl_down(acc, off);
    if ((threadIdx.x & 63) == 0) atomicAdd(out, acc * (1.0f / (float)BN));
}

extern "C" void kernel_launch(void* const* d_in, const int* in_sizes, int n_in,
                              void* d_out, int out_size, void* d_ws, size_t ws_size,
                              hipStream_t stream) {
    const float* pred = (const float*)d_in[0];
    const float* gt = (const float*)d_in[1];
    float* out = (float*)d_out;

    zero_out_kernel<<<1, 64, 0, stream>>>(out);
    sort_clouds<<<dim3(NCLOUD), 1024, 0, stream>>>(pred, gt);
    knn_window<<<dim3(NCLOUD, NPTS / QPB), 128, 0, stream>>>();
    cos_loss_kernel<<<dim3(BN / 256), 256, 0, stream>>>(out);
}